// Round 1
// baseline (1147.092 us; speedup 1.0000x reference)
//
#include <hip/hip_runtime.h>
#include <math.h>

#define B_ 4
#define T_ 2048
#define C_ 1024
#define H_ 128

// ---------------------------------------------------------------------------
// Kernel A: q/k/v projections. Block = 128 threads (h = tid), 8 rows of x
// staged in LDS (broadcast reads), W streamed from global (coalesced, L2).
// ---------------------------------------------------------------------------
__global__ __launch_bounds__(128) void qkv_kernel(
    const float* __restrict__ x,  const float* __restrict__ Wq,
    const float* __restrict__ Wk, const float* __restrict__ Wv,
    float* __restrict__ Q, float* __restrict__ K, float* __restrict__ V)
{
    __shared__ float xs[8][C_];                 // 32 KB
    const int r0 = blockIdx.x * 8;              // base row in [0, B*T)
    const int h  = threadIdx.x;                 // 0..127

    // cooperative float4 load of 8 rows x 1024 c
    const float4* xg  = (const float4*)(x + (size_t)r0 * C_);
    float4*       xs4 = (float4*)&xs[0][0];
    for (int i = threadIdx.x; i < 8 * C_ / 4; i += 128)
        xs4[i] = xg[i];
    __syncthreads();

    float aq[8], ak[8], av[8];
    #pragma unroll
    for (int r = 0; r < 8; ++r) { aq[r] = 0.f; ak[r] = 0.f; av[r] = 0.f; }

    #pragma unroll 4
    for (int c = 0; c < C_; ++c) {
        float wq = Wq[c * H_ + h];
        float wk = Wk[c * H_ + h];
        float wv = Wv[c * H_ + h];
        #pragma unroll
        for (int r = 0; r < 8; ++r) {
            float xv = xs[r][c];                // LDS broadcast
            aq[r] += xv * wq;
            ak[r] += xv * wk;
            av[r] += xv * wv;
        }
    }
    #pragma unroll
    for (int r = 0; r < 8; ++r) {
        size_t o = (size_t)(r0 + r) * H_ + h;
        Q[o] = aq[r]; K[o] = ak[r]; V[o] = av[r];
    }
}

// ---------------------------------------------------------------------------
// Kernel B1: S[b,t,s] = scale * dot(Q[b,t,:], K[b,s,:]) for lower triangle
// (s <= t at tile granularity). 64x64 tile, 256 threads, 4x4 micro-tile.
// Q tile in LDS (stride 132: float4-aligned, worst 2-way bank alias = free).
// K read directly from global as float4 (32 KB tile lives in L1/L2).
// ---------------------------------------------------------------------------
__global__ __launch_bounds__(256) void scores_kernel(
    const float* __restrict__ Q, const float* __restrict__ K,
    float* __restrict__ S)
{
    const int si = blockIdx.x, ti = blockIdx.y, b = blockIdx.z;
    if (si > ti) return;                        // upper-triangle tiles unused
    const int t0 = ti * 64, s0 = si * 64;

    const float* Qb = Q + (size_t)b * T_ * H_;
    const float* Kb = K + (size_t)b * T_ * H_;

    __shared__ float Qs[64 * 132];              // row stride 132 floats
    for (int i = threadIdx.x; i < 64 * 32; i += 256) {
        int r = i >> 5, c4 = i & 31;
        float4 v = *(const float4*)&Qb[(size_t)(t0 + r) * H_ + c4 * 4];
        *(float4*)&Qs[r * 132 + c4 * 4] = v;
    }
    __syncthreads();

    const int tx = threadIdx.x & 15;            // s direction (4 cols each)
    const int ty = threadIdx.x >> 4;            // t direction (4 rows each)

    float acc[4][4];
    #pragma unroll
    for (int i = 0; i < 4; ++i)
        #pragma unroll
        for (int j = 0; j < 4; ++j) acc[i][j] = 0.f;

    const float* K0 = &Kb[(size_t)(s0 + tx * 4) * H_];

    for (int c4 = 0; c4 < 32; ++c4) {
        float4 kv[4];
        #pragma unroll
        for (int j = 0; j < 4; ++j)
            kv[j] = *(const float4*)&K0[(size_t)j * H_ + c4 * 4];
        #pragma unroll
        for (int i = 0; i < 4; ++i) {
            float4 qv = *(const float4*)&Qs[(ty * 4 + i) * 132 + c4 * 4];
            #pragma unroll
            for (int j = 0; j < 4; ++j) {
                acc[i][j] += qv.x * kv[j].x + qv.y * kv[j].y
                           + qv.z * kv[j].z + qv.w * kv[j].w;
            }
        }
    }

    const float scale = 0.08838834764831845f;   // 1/sqrt(128)
    #pragma unroll
    for (int i = 0; i < 4; ++i) {
        float4 o;
        o.x = acc[i][0] * scale; o.y = acc[i][1] * scale;
        o.z = acc[i][2] * scale; o.w = acc[i][3] * scale;
        *(float4*)&S[((size_t)b * T_ + t0 + ty * 4 + i) * T_ + s0 + tx * 4] = o;
    }
}

// ---------------------------------------------------------------------------
// Kernel B2: per-KEY-column softmax stats (softmax is over the QUERY axis!).
// For column s: m[s] = max_{t>=s} S[t,s], l[s] = sum_{t>=s} exp(S[t,s]-m[s]).
// Block owns 256 consecutive columns, sweeps rows (coalesced reads).
// ---------------------------------------------------------------------------
__global__ __launch_bounds__(256) void stats_kernel(
    const float* __restrict__ S, float* __restrict__ m, float* __restrict__ l)
{
    const int b  = blockIdx.y;
    const int s0 = blockIdx.x * 256;
    const int s  = s0 + threadIdx.x;
    const float* Sb = S + (size_t)b * T_ * T_;

    float mx = -INFINITY, sum = 0.f;
    for (int t = s0; t < T_; ++t) {
        if (t >= s) {                           // only lower triangle is valid
            float v  = Sb[(size_t)t * T_ + s];
            float mn = fmaxf(mx, v);
            sum = sum * __expf(mx - mn) + __expf(v - mn);
            mx  = mn;
        }
    }
    m[b * T_ + s] = mx;
    l[b * T_ + s] = sum;
}

// ---------------------------------------------------------------------------
// Kernel B3: out[b,t,h] = sum_{s<=t} exp(S[t,s]-m[s])/l[s] * V[s,h].
// Block = 128 threads (h = tid), 8 query rows per block -> each V read is
// reused 8x. Weights for a 128-wide s-chunk staged in LDS.
// ---------------------------------------------------------------------------
#define TM3 8
__global__ __launch_bounds__(128) void out_kernel(
    const float* __restrict__ S, const float* __restrict__ V,
    const float* __restrict__ m, const float* __restrict__ l,
    float* __restrict__ out)
{
    const int b  = blockIdx.y;
    const int t0 = blockIdx.x * TM3;
    const int h  = threadIdx.x;
    const float* Sb = S + (size_t)b * T_ * T_;
    const float* Vb = V + (size_t)b * T_ * H_;

    __shared__ float wl[128][TM3];              // [s-chunk][row], 4 KB

    float acc[TM3];
    #pragma unroll
    for (int r = 0; r < TM3; ++r) acc[r] = 0.f;

    const int tmax = t0 + TM3 - 1;
    for (int s0 = 0; s0 <= tmax; s0 += 128) {
        const int s = s0 + threadIdx.x;         // s <= 2047 always here
        float ms = m[b * T_ + s];
        float rl = 1.0f / l[b * T_ + s];        // l >= 1 always
        #pragma unroll
        for (int r = 0; r < TM3; ++r) {
            int t = t0 + r;
            float w = 0.f;
            if (s <= t) w = __expf(Sb[(size_t)t * T_ + s] - ms) * rl;
            wl[threadIdx.x][r] = w;
        }
        __syncthreads();

        const int jend = min(128, tmax - s0 + 1);
        for (int j = 0; j < jend; ++j) {
            float vv = Vb[(size_t)(s0 + j) * H_ + h];   // coalesced 512B
            float4 w0 = *(const float4*)&wl[j][0];      // LDS broadcast
            float4 w1 = *(const float4*)&wl[j][4];
            acc[0] += w0.x * vv; acc[1] += w0.y * vv;
            acc[2] += w0.z * vv; acc[3] += w0.w * vv;
            acc[4] += w1.x * vv; acc[5] += w1.y * vv;
            acc[6] += w1.z * vv; acc[7] += w1.w * vv;
        }
        __syncthreads();
    }

    #pragma unroll
    for (int r = 0; r < TM3; ++r)
        out[((size_t)b * T_ + t0 + r) * H_ + h] = acc[r];
}

// ---------------------------------------------------------------------------
extern "C" void kernel_launch(void* const* d_in, const int* in_sizes, int n_in,
                              void* d_out, int out_size, void* d_ws, size_t ws_size,
                              hipStream_t stream) {
    const float* x  = (const float*)d_in[0];
    const float* Wq = (const float*)d_in[1];
    const float* Wk = (const float*)d_in[2];
    const float* Wv = (const float*)d_in[3];
    float* out = (float*)d_out;

    // workspace layout (floats): Q,K,V [B*T*H] each, S [B*T*T], m,l [B*T]
    float* ws = (float*)d_ws;
    float* Q = ws;
    float* K = Q + (size_t)B_ * T_ * H_;
    float* V = K + (size_t)B_ * T_ * H_;
    float* S = V + (size_t)B_ * T_ * H_;
    float* m = S + (size_t)B_ * T_ * T_;
    float* l = m + (size_t)B_ * T_;
    // total: ~80 MB

    qkv_kernel   <<<dim3(B_ * T_ / 8),      dim3(128), 0, stream>>>(x, Wq, Wk, Wv, Q, K, V);
    scores_kernel<<<dim3(32, 32, B_),       dim3(256), 0, stream>>>(Q, K, S);
    stats_kernel <<<dim3(T_ / 256, B_),     dim3(256), 0, stream>>>(S, m, l);
    out_kernel   <<<dim3(T_ / TM3, B_),     dim3(128), 0, stream>>>(S, V, m, l, out);
}

// Round 2
// 601.188 us; speedup vs baseline: 1.9080x; 1.9080x over previous
//
#include <hip/hip_runtime.h>
#include <math.h>

#define B_ 4
#define T_ 2048
#define C_ 1024
#define H_ 128
#define RCHUNK 128                 // rows per stats partial chunk
#define NCHUNK (T_ / RCHUNK)       // 16 chunks

// ---------------------------------------------------------------------------
// Kernel A: q/k/v projections. Block = 128 threads (h = tid), 8 rows of x
// staged in LDS (broadcast reads), W streamed from global (coalesced, L2).
// ---------------------------------------------------------------------------
__global__ __launch_bounds__(128) void qkv_kernel(
    const float* __restrict__ x,  const float* __restrict__ Wq,
    const float* __restrict__ Wk, const float* __restrict__ Wv,
    float* __restrict__ Q, float* __restrict__ K, float* __restrict__ V)
{
    __shared__ float xs[8][C_];                 // 32 KB
    const int r0 = blockIdx.x * 8;              // base row in [0, B*T)
    const int h  = threadIdx.x;                 // 0..127

    const float4* xg  = (const float4*)(x + (size_t)r0 * C_);
    float4*       xs4 = (float4*)&xs[0][0];
    for (int i = threadIdx.x; i < 8 * C_ / 4; i += 128)
        xs4[i] = xg[i];
    __syncthreads();

    float aq[8], ak[8], av[8];
    #pragma unroll
    for (int r = 0; r < 8; ++r) { aq[r] = 0.f; ak[r] = 0.f; av[r] = 0.f; }

    #pragma unroll 4
    for (int c = 0; c < C_; ++c) {
        float wq = Wq[c * H_ + h];
        float wk = Wk[c * H_ + h];
        float wv = Wv[c * H_ + h];
        #pragma unroll
        for (int r = 0; r < 8; ++r) {
            float xv = xs[r][c];                // LDS broadcast
            aq[r] += xv * wq;
            ak[r] += xv * wk;
            av[r] += xv * wv;
        }
    }
    #pragma unroll
    for (int r = 0; r < 8; ++r) {
        size_t o = (size_t)(r0 + r) * H_ + h;
        Q[o] = aq[r]; K[o] = ak[r]; V[o] = av[r];
    }
}

// ---------------------------------------------------------------------------
// Kernel B1: S[b,t,s] = scale * dot(Q[b,t,:], K[b,s,:]) for lower triangle
// (s <= t at tile granularity). 64x64 tile, 256 threads, 4x4 micro-tile.
// ---------------------------------------------------------------------------
__global__ __launch_bounds__(256) void scores_kernel(
    const float* __restrict__ Q, const float* __restrict__ K,
    float* __restrict__ S)
{
    const int si = blockIdx.x, ti = blockIdx.y, b = blockIdx.z;
    if (si > ti) return;                        // upper-triangle tiles unused
    const int t0 = ti * 64, s0 = si * 64;

    const float* Qb = Q + (size_t)b * T_ * H_;
    const float* Kb = K + (size_t)b * T_ * H_;

    __shared__ float Qs[64 * 132];              // row stride 132 floats
    for (int i = threadIdx.x; i < 64 * 32; i += 256) {
        int r = i >> 5, c4 = i & 31;
        float4 v = *(const float4*)&Qb[(size_t)(t0 + r) * H_ + c4 * 4];
        *(float4*)&Qs[r * 132 + c4 * 4] = v;
    }
    __syncthreads();

    const int tx = threadIdx.x & 15;            // s direction (4 cols each)
    const int ty = threadIdx.x >> 4;            // t direction (4 rows each)

    float acc[4][4];
    #pragma unroll
    for (int i = 0; i < 4; ++i)
        #pragma unroll
        for (int j = 0; j < 4; ++j) acc[i][j] = 0.f;

    const float* K0 = &Kb[(size_t)(s0 + tx * 4) * H_];

    for (int c4 = 0; c4 < 32; ++c4) {
        float4 kv[4];
        #pragma unroll
        for (int j = 0; j < 4; ++j)
            kv[j] = *(const float4*)&K0[(size_t)j * H_ + c4 * 4];
        #pragma unroll
        for (int i = 0; i < 4; ++i) {
            float4 qv = *(const float4*)&Qs[(ty * 4 + i) * 132 + c4 * 4];
            #pragma unroll
            for (int j = 0; j < 4; ++j) {
                acc[i][j] += qv.x * kv[j].x + qv.y * kv[j].y
                           + qv.z * kv[j].z + qv.w * kv[j].w;
            }
        }
    }

    const float scale = 0.08838834764831845f;   // 1/sqrt(128)
    #pragma unroll
    for (int i = 0; i < 4; ++i) {
        float4 o;
        o.x = acc[i][0] * scale; o.y = acc[i][1] * scale;
        o.z = acc[i][2] * scale; o.w = acc[i][3] * scale;
        *(float4*)&S[((size_t)b * T_ + t0 + ty * 4 + i) * T_ + s0 + tx * 4] = o;
    }
}

// ---------------------------------------------------------------------------
// Kernel B2a: PARTIAL per-key-column stats over a 128-row chunk.
// grid = (T/256 col-blocks, NCHUNK row-chunks, B), block = 256.
// Column s, rows t in [r0, r0+RCHUNK) ∩ [s, T). Coalesced row sweeps.
// Writes pm[b][chunk][s], pl[b][chunk][s]  (staged in d_out, 1 MB).
// ---------------------------------------------------------------------------
__global__ __launch_bounds__(256) void stats_partial_kernel(
    const float* __restrict__ S, float* __restrict__ pm, float* __restrict__ pl)
{
    const int b  = blockIdx.z;
    const int r0 = blockIdx.y * RCHUNK;
    const int s0 = blockIdx.x * 256;
    const int s  = s0 + threadIdx.x;
    const size_t oidx = ((size_t)b * NCHUNK + blockIdx.y) * T_ + s;

    float mx = -INFINITY, sum = 0.f;
    if (r0 + RCHUNK > s0) {                     // chunk intersects triangle
        const float* Sb = S + (size_t)b * T_ * T_;
        const int tstart = r0;
        const int tend   = r0 + RCHUNK;         // <= T_ always
        for (int t = tstart; t < tend; ++t) {
            if (t >= s) {
                float v  = Sb[(size_t)t * T_ + s];
                float mn = fmaxf(mx, v);
                sum = sum * __expf(mx - mn) + __expf(v - mn);
                mx  = mn;
            }
        }
    }
    pm[oidx] = mx;
    pl[oidx] = sum;
}

// ---------------------------------------------------------------------------
// Kernel B2b: combine NCHUNK partials per column: M = max m_c,
// L = sum l_c * exp(m_c - M).  B*T threads total.
// ---------------------------------------------------------------------------
__global__ __launch_bounds__(256) void stats_reduce_kernel(
    const float* __restrict__ pm, const float* __restrict__ pl,
    float* __restrict__ m, float* __restrict__ l)
{
    const int idx = blockIdx.x * 256 + threadIdx.x;   // b*T + s
    const int b = idx / T_, s = idx - b * T_;

    float M = -INFINITY;
    #pragma unroll
    for (int c = 0; c < NCHUNK; ++c)
        M = fmaxf(M, pm[((size_t)b * NCHUNK + c) * T_ + s]);

    float L = 0.f;
    #pragma unroll
    for (int c = 0; c < NCHUNK; ++c) {
        float mc = pm[((size_t)b * NCHUNK + c) * T_ + s];
        float lc = pl[((size_t)b * NCHUNK + c) * T_ + s];
        if (lc > 0.f) L += lc * __expf(mc - M);
    }
    m[idx] = M;
    l[idx] = L;
}

// ---------------------------------------------------------------------------
// Kernel B3: out[b,t,h] = sum_{s<=t} exp(S[t,s]-m[s])/l[s] * V[s,h].
// ---------------------------------------------------------------------------
#define TM3 8
__global__ __launch_bounds__(128) void out_kernel(
    const float* __restrict__ S, const float* __restrict__ V,
    const float* __restrict__ m, const float* __restrict__ l,
    float* __restrict__ out)
{
    const int b  = blockIdx.y;
    const int t0 = blockIdx.x * TM3;
    const int h  = threadIdx.x;
    const float* Sb = S + (size_t)b * T_ * T_;
    const float* Vb = V + (size_t)b * T_ * H_;

    __shared__ float wl[128][TM3];              // [s-chunk][row], 4 KB

    float acc[TM3];
    #pragma unroll
    for (int r = 0; r < TM3; ++r) acc[r] = 0.f;

    const int tmax = t0 + TM3 - 1;
    for (int s0 = 0; s0 <= tmax; s0 += 128) {
        const int s = s0 + threadIdx.x;         // s <= 2047 always here
        float ms = m[b * T_ + s];
        float rl = 1.0f / l[b * T_ + s];        // l >= 1 always
        #pragma unroll
        for (int r = 0; r < TM3; ++r) {
            int t = t0 + r;
            float w = 0.f;
            if (s <= t) w = __expf(Sb[(size_t)t * T_ + s] - ms) * rl;
            wl[threadIdx.x][r] = w;
        }
        __syncthreads();

        const int jend = min(128, tmax - s0 + 1);
        for (int j = 0; j < jend; ++j) {
            float vv = Vb[(size_t)(s0 + j) * H_ + h];   // coalesced 512B
            float4 w0 = *(const float4*)&wl[j][0];      // LDS broadcast
            float4 w1 = *(const float4*)&wl[j][4];
            acc[0] += w0.x * vv; acc[1] += w0.y * vv;
            acc[2] += w0.z * vv; acc[3] += w0.w * vv;
            acc[4] += w1.x * vv; acc[5] += w1.y * vv;
            acc[6] += w1.z * vv; acc[7] += w1.w * vv;
        }
        __syncthreads();
    }

    #pragma unroll
    for (int r = 0; r < TM3; ++r)
        out[((size_t)b * T_ + t0 + r) * H_ + h] = acc[r];
}

// ---------------------------------------------------------------------------
extern "C" void kernel_launch(void* const* d_in, const int* in_sizes, int n_in,
                              void* d_out, int out_size, void* d_ws, size_t ws_size,
                              hipStream_t stream) {
    const float* x  = (const float*)d_in[0];
    const float* Wq = (const float*)d_in[1];
    const float* Wk = (const float*)d_in[2];
    const float* Wv = (const float*)d_in[3];
    float* out = (float*)d_out;

    // workspace layout (floats): Q,K,V [B*T*H] each, S [B*T*T], m,l [B*T]
    float* ws = (float*)d_ws;
    float* Q = ws;
    float* K = Q + (size_t)B_ * T_ * H_;
    float* V = K + (size_t)B_ * T_ * H_;
    float* S = V + (size_t)B_ * T_ * H_;
    float* m = S + (size_t)B_ * T_ * T_;
    float* l = m + (size_t)B_ * T_;
    // total: ~80.8 MB

    // stats partials live in d_out (B*NCHUNK*T floats * 2 = 1 MB << 4 MB);
    // d_out is consumed by stats_reduce before out_kernel overwrites it.
    float* pm = (float*)d_out;
    float* pl = pm + (size_t)B_ * NCHUNK * T_;

    qkv_kernel   <<<dim3(B_ * T_ / 8),            dim3(128), 0, stream>>>(x, Wq, Wk, Wv, Q, K, V);
    scores_kernel<<<dim3(32, 32, B_),             dim3(256), 0, stream>>>(Q, K, S);
    stats_partial_kernel<<<dim3(T_ / 256, NCHUNK, B_), dim3(256), 0, stream>>>(S, pm, pl);
    stats_reduce_kernel <<<dim3(B_ * T_ / 256),   dim3(256), 0, stream>>>(pm, pl, m, l);
    out_kernel   <<<dim3(T_ / TM3, B_),           dim3(128), 0, stream>>>(S, V, m, l, out);
}

// Round 3
// 482.728 us; speedup vs baseline: 2.3763x; 1.2454x over previous
//
#include <hip/hip_runtime.h>
#include <math.h>

#define B_ 4
#define T_ 2048
#define C_ 1024
#define H_ 128
#define RCHUNK 128                 // rows per stats partial chunk
#define NCHUNK (T_ / RCHUNK)       // 16 chunks

typedef unsigned short u16;
typedef short short8 __attribute__((ext_vector_type(8)));   // 8 bf16 = 4 VGPRs
typedef float floatx4 __attribute__((ext_vector_type(4)));  // MFMA C/D

// fp32 -> bf16 round-to-nearest-even (no NaN handling needed here)
__device__ __forceinline__ u16 f2bf(float f) {
    union { float f; unsigned int u; } v; v.f = f;
    return (u16)((v.u + 0x7fffu + ((v.u >> 16) & 1u)) >> 16);
}

// ---------------------------------------------------------------------------
// Kernel A: q/k/v projections (fp32 VALU), emitting bf16 Q,K (row-major
// [B*T][H]) and bf16 V TRANSPOSED ([B][H][T]) for MFMA B-fragments.
// ---------------------------------------------------------------------------
__global__ __launch_bounds__(128) void qkv_kernel(
    const float* __restrict__ x,  const float* __restrict__ Wq,
    const float* __restrict__ Wk, const float* __restrict__ Wv,
    u16* __restrict__ Qb, u16* __restrict__ Kb, u16* __restrict__ Vt)
{
    __shared__ float xs[8][C_];                 // 32 KB
    const int r0 = blockIdx.x * 8;              // base row in [0, B*T)
    const int h  = threadIdx.x;                 // 0..127

    const float4* xg  = (const float4*)(x + (size_t)r0 * C_);
    float4*       xs4 = (float4*)&xs[0][0];
    for (int i = threadIdx.x; i < 8 * C_ / 4; i += 128)
        xs4[i] = xg[i];
    __syncthreads();

    float aq[8], ak[8], av[8];
    #pragma unroll
    for (int r = 0; r < 8; ++r) { aq[r] = 0.f; ak[r] = 0.f; av[r] = 0.f; }

    #pragma unroll 4
    for (int c = 0; c < C_; ++c) {
        float wq = Wq[c * H_ + h];
        float wk = Wk[c * H_ + h];
        float wv = Wv[c * H_ + h];
        #pragma unroll
        for (int r = 0; r < 8; ++r) {
            float xv = xs[r][c];                // LDS broadcast
            aq[r] += xv * wq;
            ak[r] += xv * wk;
            av[r] += xv * wv;
        }
    }
    #pragma unroll
    for (int r = 0; r < 8; ++r) {
        size_t o = (size_t)(r0 + r) * H_ + h;
        Qb[o] = f2bf(aq[r]);
        Kb[o] = f2bf(ak[r]);
    }
    // V transposed: Vt[b][h][t], 8 consecutive t per lane -> one 16B store
    const int b = r0 / T_;
    const int t = r0 - b * T_;
    short8 vt;
    #pragma unroll
    for (int r = 0; r < 8; ++r) vt[r] = (short)f2bf(av[r]);
    *(short8*)&Vt[((size_t)b * H_ + h) * T_ + t] = vt;
}

// ---------------------------------------------------------------------------
// Kernel B1 (MFMA): S[b,t,s] = scale * Q·K^T, lower-triangle tiles only.
// Block 256 thr = 4 waves; tile 128(t) x 64(s); K-dim H=128 in 4 MFMA steps.
// LDS stride 136 bf16 (=272 B: 16B-aligned rows, 2-way bank alias = free).
// ---------------------------------------------------------------------------
__global__ __launch_bounds__(256) void scores_kernel(
    const u16* __restrict__ Qb, const u16* __restrict__ Kb,
    float* __restrict__ S)
{
    const int si = blockIdx.x;                  // 0..31 (s tile, 64 wide)
    const int ti = blockIdx.y;                  // 0..15 (t tile, 128 tall)
    const int b  = blockIdx.z;
    if (si > 2 * ti + 1) return;                // strictly-upper tiles unused
    const int t0 = ti * 128, s0 = si * 64;

    __shared__ u16 Qs[128 * 136];               // 34.8 KB
    __shared__ u16 Ks[64 * 136];                // 17.4 KB

    const u16* Qg = Qb + ((size_t)b * T_ + t0) * H_;
    const u16* Kg = Kb + ((size_t)b * T_ + s0) * H_;

    for (int i = threadIdx.x; i < 128 * 16; i += 256) {   // Q: 128 rows x 16 f4
        int r = i >> 4, c = i & 15;
        *(float4*)&Qs[r * 136 + c * 8] = *(const float4*)&Qg[(size_t)r * H_ + c * 8];
    }
    for (int i = threadIdx.x; i < 64 * 16; i += 256) {    // K: 64 rows x 16 f4
        int r = i >> 4, c = i & 15;
        *(float4*)&Ks[r * 136 + c * 8] = *(const float4*)&Kg[(size_t)r * H_ + c * 8];
    }
    __syncthreads();

    const int w    = threadIdx.x >> 6;          // wave 0..3 -> t rows [32w,32w+32)
    const int lane = threadIdx.x & 63;
    const int q    = lane >> 4, r = lane & 15;

    floatx4 acc[2][4] = {};                     // [m-tile][n-tile]
    #pragma unroll
    for (int kk = 0; kk < 4; ++kk) {
        short8 a0 = *(const short8*)&Qs[(32 * w +      r) * 136 + kk * 32 + q * 8];
        short8 a1 = *(const short8*)&Qs[(32 * w + 16 + r) * 136 + kk * 32 + q * 8];
        #pragma unroll
        for (int nt = 0; nt < 4; ++nt) {
            short8 bf = *(const short8*)&Ks[(16 * nt + r) * 136 + kk * 32 + q * 8];
            acc[0][nt] = __builtin_amdgcn_mfma_f32_16x16x32_bf16(a0, bf, acc[0][nt], 0, 0, 0);
            acc[1][nt] = __builtin_amdgcn_mfma_f32_16x16x32_bf16(a1, bf, acc[1][nt], 0, 0, 0);
        }
    }

    const float scale = 0.08838834764831845f;   // 1/sqrt(128)
    #pragma unroll
    for (int mt = 0; mt < 2; ++mt)
        #pragma unroll
        for (int nt = 0; nt < 4; ++nt)
            #pragma unroll
            for (int reg = 0; reg < 4; ++reg) {
                int t = t0 + 32 * w + 16 * mt + q * 4 + reg;   // C/D row map
                int s = s0 + 16 * nt + r;                      // C/D col map
                S[((size_t)b * T_ + t) * T_ + s] = acc[mt][nt][reg] * scale;
            }
}

// ---------------------------------------------------------------------------
// Kernel B2a: PARTIAL per-key-column stats over a 128-row chunk (unchanged).
// ---------------------------------------------------------------------------
__global__ __launch_bounds__(256) void stats_partial_kernel(
    const float* __restrict__ S, float* __restrict__ pm, float* __restrict__ pl)
{
    const int b  = blockIdx.z;
    const int r0 = blockIdx.y * RCHUNK;
    const int s0 = blockIdx.x * 256;
    const int s  = s0 + threadIdx.x;
    const size_t oidx = ((size_t)b * NCHUNK + blockIdx.y) * T_ + s;

    float mx = -INFINITY, sum = 0.f;
    if (r0 + RCHUNK > s0) {
        const float* Sb = S + (size_t)b * T_ * T_;
        for (int t = r0; t < r0 + RCHUNK; ++t) {
            if (t >= s) {
                float v  = Sb[(size_t)t * T_ + s];
                float mn = fmaxf(mx, v);
                sum = sum * __expf(mx - mn) + __expf(v - mn);
                mx  = mn;
            }
        }
    }
    pm[oidx] = mx;
    pl[oidx] = sum;
}

// ---------------------------------------------------------------------------
// Kernel B2b: combine partials (unchanged).
// ---------------------------------------------------------------------------
__global__ __launch_bounds__(256) void stats_reduce_kernel(
    const float* __restrict__ pm, const float* __restrict__ pl,
    float* __restrict__ m, float* __restrict__ l)
{
    const int idx = blockIdx.x * 256 + threadIdx.x;   // b*T + s
    const int b = idx / T_, s = idx - b * T_;

    float M = -INFINITY;
    #pragma unroll
    for (int c = 0; c < NCHUNK; ++c)
        M = fmaxf(M, pm[((size_t)b * NCHUNK + c) * T_ + s]);

    float L = 0.f;
    #pragma unroll
    for (int c = 0; c < NCHUNK; ++c) {
        float mc = pm[((size_t)b * NCHUNK + c) * T_ + s];
        float lc = pl[((size_t)b * NCHUNK + c) * T_ + s];
        if (lc > 0.f) L += lc * __expf(mc - M);
    }
    m[idx] = M;
    l[idx] = L;
}

// ---------------------------------------------------------------------------
// Kernel B3 (MFMA): out = P @ V with P = exp(S - m[s]) / l[s], s <= t.
// Block 128 thr = 2 waves; 32 t-rows per block; s swept in 64-chunks.
// P built in bf16 LDS (masked), V^T chunk staged from global bf16.
// ---------------------------------------------------------------------------
__global__ __launch_bounds__(128) void out_kernel(
    const float* __restrict__ S, const u16* __restrict__ Vt,
    const float* __restrict__ m, const float* __restrict__ l,
    float* __restrict__ out)
{
    const int b  = blockIdx.y;
    const int tb = (int)(gridDim.x - 1 - blockIdx.x); // big tiles first
    const int t0 = tb * 32;
    const int nchunks = t0 / 64 + 1;

    __shared__ u16 Ps[32 * 72];                 // 4.6 KB  (72 = 64+8 pad)
    __shared__ u16 Vs[128 * 72];                // 18.4 KB

    const float* Sb = S + (size_t)b * T_ * T_;
    const int w    = threadIdx.x >> 6;          // wave 0..1 -> t rows [16w,16w+16)
    const int lane = threadIdx.x & 63;
    const int q    = lane >> 4, r = lane & 15;
    const int sc   = threadIdx.x & 63;          // P-build: s within chunk
    const int tq   = threadIdx.x >> 6;          // P-build: row group 0..1

    floatx4 acc[8] = {};

    for (int ci = 0; ci < nchunks; ++ci) {
        const int s0 = ci * 64;
        const int s  = s0 + sc;
        float ms = m[b * T_ + s];
        float rl = 1.0f / l[b * T_ + s];        // l >= 1 (diagonal term)
        #pragma unroll
        for (int it = 0; it < 16; ++it) {
            int tr = tq * 16 + it;              // 0..31
            int t  = t0 + tr;
            float wgt = 0.f;
            if (s <= t) wgt = __expf(Sb[(size_t)t * T_ + s] - ms) * rl;
            Ps[tr * 72 + sc] = f2bf(wgt);
        }
        // V^T chunk: 128 h-rows x 64 s (bf16) = 1024 f4 / 128 thr = 8 each
        for (int i = threadIdx.x; i < 128 * 8; i += 128) {
            int h = i >> 3, c = i & 7;
            *(float4*)&Vs[h * 72 + c * 8] =
                *(const float4*)&Vt[((size_t)b * H_ + h) * T_ + s0 + c * 8];
        }
        __syncthreads();

        #pragma unroll
        for (int kk = 0; kk < 2; ++kk) {
            short8 af = *(const short8*)&Ps[(16 * w + r) * 72 + kk * 32 + q * 8];
            #pragma unroll
            for (int nt = 0; nt < 8; ++nt) {
                short8 bf = *(const short8*)&Vs[(16 * nt + r) * 72 + kk * 32 + q * 8];
                acc[nt] = __builtin_amdgcn_mfma_f32_16x16x32_bf16(af, bf, acc[nt], 0, 0, 0);
            }
        }
        __syncthreads();
    }

    #pragma unroll
    for (int nt = 0; nt < 8; ++nt)
        #pragma unroll
        for (int reg = 0; reg < 4; ++reg) {
            int t = t0 + 16 * w + q * 4 + reg;
            int h = 16 * nt + r;
            out[((size_t)b * T_ + t) * H_ + h] = acc[nt][reg];
        }
}

// ---------------------------------------------------------------------------
extern "C" void kernel_launch(void* const* d_in, const int* in_sizes, int n_in,
                              void* d_out, int out_size, void* d_ws, size_t ws_size,
                              hipStream_t stream) {
    const float* x  = (const float*)d_in[0];
    const float* Wq = (const float*)d_in[1];
    const float* Wk = (const float*)d_in[2];
    const float* Wv = (const float*)d_in[3];
    float* out = (float*)d_out;

    // workspace: S fp32 [B*T*T], m,l fp32 [B*T], Qb,Kb bf16 [B*T*H], Vt bf16 [B*H*T]
    float* S  = (float*)d_ws;                          // 64 MB
    float* m  = S + (size_t)B_ * T_ * T_;
    float* l  = m + (size_t)B_ * T_;
    u16*   Qb = (u16*)(l + (size_t)B_ * T_);
    u16*   Kb = Qb + (size_t)B_ * T_ * H_;             // 2 MB each
    u16*   Vt = Kb + (size_t)B_ * T_ * H_;
    // total ~70.1 MB (round-1 layout used 80.8 MB, so ws_size suffices)

    // stats partials staged in d_out (1 MB << 4 MB), consumed before out_kernel
    float* pm = (float*)d_out;
    float* pl = pm + (size_t)B_ * NCHUNK * T_;

    qkv_kernel   <<<dim3(B_ * T_ / 8),            dim3(128), 0, stream>>>(x, Wq, Wk, Wv, Qb, Kb, Vt);
    scores_kernel<<<dim3(32, 16, B_),             dim3(256), 0, stream>>>(Qb, Kb, S);
    stats_partial_kernel<<<dim3(T_ / 256, NCHUNK, B_), dim3(256), 0, stream>>>(S, pm, pl);
    stats_reduce_kernel <<<dim3(B_ * T_ / 256),   dim3(256), 0, stream>>>(pm, pl, m, l);
    out_kernel   <<<dim3(T_ / 32, B_),            dim3(128), 0, stream>>>(S, Vt, m, l, out);
}

// Round 4
// 300.407 us; speedup vs baseline: 3.8185x; 1.6069x over previous
//
#include <hip/hip_runtime.h>
#include <math.h>

#define B_ 4
#define T_ 2048
#define C_ 1024
#define H_ 128
#define RCHUNK 128                 // rows per stats partial chunk
#define NCHUNK (T_ / RCHUNK)       // 16 chunks

typedef unsigned short u16;
typedef short short8 __attribute__((ext_vector_type(8)));   // 8 bf16 = 4 VGPRs
typedef float floatx4 __attribute__((ext_vector_type(4)));  // MFMA C/D

// fp32 -> bf16 round-to-nearest-even (no NaN handling needed here)
__device__ __forceinline__ u16 f2bf(float f) {
    union { float f; unsigned int u; } v; v.f = f;
    return (u16)((v.u + 0x7fffu + ((v.u >> 16) & 1u)) >> 16);
}

// ---------------------------------------------------------------------------
// Kernel A: q/k/v projections (fp32 VALU), emitting bf16 Q,K (row-major
// [B*T][H]) and bf16 V TRANSPOSED ([B][H][T]) for MFMA B-fragments.
// ---------------------------------------------------------------------------
__global__ __launch_bounds__(128) void qkv_kernel(
    const float* __restrict__ x,  const float* __restrict__ Wq,
    const float* __restrict__ Wk, const float* __restrict__ Wv,
    u16* __restrict__ Qb, u16* __restrict__ Kb, u16* __restrict__ Vt)
{
    __shared__ float xs[8][C_];                 // 32 KB
    const int r0 = blockIdx.x * 8;              // base row in [0, B*T)
    const int h  = threadIdx.x;                 // 0..127

    const float4* xg  = (const float4*)(x + (size_t)r0 * C_);
    float4*       xs4 = (float4*)&xs[0][0];
    for (int i = threadIdx.x; i < 8 * C_ / 4; i += 128)
        xs4[i] = xg[i];
    __syncthreads();

    float aq[8], ak[8], av[8];
    #pragma unroll
    for (int r = 0; r < 8; ++r) { aq[r] = 0.f; ak[r] = 0.f; av[r] = 0.f; }

    #pragma unroll 4
    for (int c = 0; c < C_; ++c) {
        float wq = Wq[c * H_ + h];
        float wk = Wk[c * H_ + h];
        float wv = Wv[c * H_ + h];
        #pragma unroll
        for (int r = 0; r < 8; ++r) {
            float xv = xs[r][c];                // LDS broadcast
            aq[r] += xv * wq;
            ak[r] += xv * wk;
            av[r] += xv * wv;
        }
    }
    #pragma unroll
    for (int r = 0; r < 8; ++r) {
        size_t o = (size_t)(r0 + r) * H_ + h;
        Qb[o] = f2bf(aq[r]);
        Kb[o] = f2bf(ak[r]);
    }
    // V transposed: Vt[b][h][t], 8 consecutive t per lane -> one 16B store
    const int b = r0 / T_;
    const int t = r0 - b * T_;
    short8 vt;
    #pragma unroll
    for (int r = 0; r < 8; ++r) vt[r] = (short)f2bf(av[r]);
    *(short8*)&Vt[((size_t)b * H_ + h) * T_ + t] = vt;
}

// ---------------------------------------------------------------------------
// Kernel B1 (MFMA): S[b,t,s] = scale * Q·K^T, lower-triangle tiles only.
// Block 256 thr = 4 waves; tile 128(t) x 64(s); K-dim H=128 in 4 MFMA steps.
// ---------------------------------------------------------------------------
__global__ __launch_bounds__(256) void scores_kernel(
    const u16* __restrict__ Qb, const u16* __restrict__ Kb,
    float* __restrict__ S)
{
    const int si = blockIdx.x;                  // 0..31 (s tile, 64 wide)
    const int ti = blockIdx.y;                  // 0..15 (t tile, 128 tall)
    const int b  = blockIdx.z;
    if (si > 2 * ti + 1) return;                // strictly-upper tiles unused
    const int t0 = ti * 128, s0 = si * 64;

    __shared__ u16 Qs[128 * 136];               // 34.8 KB
    __shared__ u16 Ks[64 * 136];                // 17.4 KB

    const u16* Qg = Qb + ((size_t)b * T_ + t0) * H_;
    const u16* Kg = Kb + ((size_t)b * T_ + s0) * H_;

    for (int i = threadIdx.x; i < 128 * 16; i += 256) {   // Q: 128 rows x 16 f4
        int r = i >> 4, c = i & 15;
        *(float4*)&Qs[r * 136 + c * 8] = *(const float4*)&Qg[(size_t)r * H_ + c * 8];
    }
    for (int i = threadIdx.x; i < 64 * 16; i += 256) {    // K: 64 rows x 16 f4
        int r = i >> 4, c = i & 15;
        *(float4*)&Ks[r * 136 + c * 8] = *(const float4*)&Kg[(size_t)r * H_ + c * 8];
    }
    __syncthreads();

    const int w    = threadIdx.x >> 6;          // wave 0..3 -> t rows [32w,32w+32)
    const int lane = threadIdx.x & 63;
    const int q    = lane >> 4, r = lane & 15;

    floatx4 acc[2][4] = {};                     // [m-tile][n-tile]
    #pragma unroll
    for (int kk = 0; kk < 4; ++kk) {
        short8 a0 = *(const short8*)&Qs[(32 * w +      r) * 136 + kk * 32 + q * 8];
        short8 a1 = *(const short8*)&Qs[(32 * w + 16 + r) * 136 + kk * 32 + q * 8];
        #pragma unroll
        for (int nt = 0; nt < 4; ++nt) {
            short8 bf = *(const short8*)&Ks[(16 * nt + r) * 136 + kk * 32 + q * 8];
            acc[0][nt] = __builtin_amdgcn_mfma_f32_16x16x32_bf16(a0, bf, acc[0][nt], 0, 0, 0);
            acc[1][nt] = __builtin_amdgcn_mfma_f32_16x16x32_bf16(a1, bf, acc[1][nt], 0, 0, 0);
        }
    }

    const float scale = 0.08838834764831845f;   // 1/sqrt(128)
    #pragma unroll
    for (int mt = 0; mt < 2; ++mt)
        #pragma unroll
        for (int nt = 0; nt < 4; ++nt)
            #pragma unroll
            for (int reg = 0; reg < 4; ++reg) {
                int t = t0 + 32 * w + 16 * mt + q * 4 + reg;   // C/D row map
                int s = s0 + 16 * nt + r;                      // C/D col map
                S[((size_t)b * T_ + t) * T_ + s] = acc[mt][nt][reg] * scale;
            }
}

// ---------------------------------------------------------------------------
// Kernel B2a: PARTIAL per-key-column stats over a 128-row chunk (unchanged).
// ---------------------------------------------------------------------------
__global__ __launch_bounds__(256) void stats_partial_kernel(
    const float* __restrict__ S, float* __restrict__ pm, float* __restrict__ pl)
{
    const int b  = blockIdx.z;
    const int r0 = blockIdx.y * RCHUNK;
    const int s0 = blockIdx.x * 256;
    const int s  = s0 + threadIdx.x;
    const size_t oidx = ((size_t)b * NCHUNK + blockIdx.y) * T_ + s;

    float mx = -INFINITY, sum = 0.f;
    if (r0 + RCHUNK > s0) {
        const float* Sb = S + (size_t)b * T_ * T_;
        for (int t = r0; t < r0 + RCHUNK; ++t) {
            if (t >= s) {
                float v  = Sb[(size_t)t * T_ + s];
                float mn = fmaxf(mx, v);
                sum = sum * __expf(mx - mn) + __expf(v - mn);
                mx  = mn;
            }
        }
    }
    pm[oidx] = mx;
    pl[oidx] = sum;
}

// ---------------------------------------------------------------------------
// Kernel B2b: combine partials. NOTE: now stores 1/L (out_kernel wants the
// reciprocal; L >= 1 always since the diagonal term contributes exp(0)).
// ---------------------------------------------------------------------------
__global__ __launch_bounds__(256) void stats_reduce_kernel(
    const float* __restrict__ pm, const float* __restrict__ pl,
    float* __restrict__ m, float* __restrict__ linv)
{
    const int idx = blockIdx.x * 256 + threadIdx.x;   // b*T + s
    const int b = idx / T_, s = idx - b * T_;

    float M = -INFINITY;
    #pragma unroll
    for (int c = 0; c < NCHUNK; ++c)
        M = fmaxf(M, pm[((size_t)b * NCHUNK + c) * T_ + s]);

    float L = 0.f;
    #pragma unroll
    for (int c = 0; c < NCHUNK; ++c) {
        float mc = pm[((size_t)b * NCHUNK + c) * T_ + s];
        float lc = pl[((size_t)b * NCHUNK + c) * T_ + s];
        if (lc > 0.f) L += lc * __expf(mc - M);
    }
    m[idx]    = M;
    linv[idx] = 1.0f / L;
}

// ---------------------------------------------------------------------------
// Kernel B3 (MFMA, register-resident): out = P @ V, P = exp(S-m[s])*linv[s],
// masked s <= t.  Block = 256 thr = 4 waves, ONE 16-row t-tile per block;
// wave w handles s-chunks ci ≡ w (mod 4) -> 4-way split-s parallelism.
// A-fragment (P) built in registers from coalesced S/m/linv loads (lane
// (q,r): row t=t0+r, k-run s=s0+kk*32+q*8..+7).  B-fragment read DIRECTLY
// from global Vt[b][h][t] (16B contiguous).  No LDS/syncs in the main loop;
// one cross-wave LDS reduction at the end.  No atomics, no extra workspace.
// ---------------------------------------------------------------------------
__global__ __launch_bounds__(256) void out_kernel(
    const float* __restrict__ S, const u16* __restrict__ Vt,
    const float* __restrict__ m, const float* __restrict__ linv,
    float* __restrict__ out)
{
    const int b  = blockIdx.y;
    const int tb = (int)(gridDim.x - 1 - blockIdx.x); // heavy tiles first
    const int t0 = tb * 16;
    const int nchunks = (t0 + 79) >> 6;               // s0 <= t0+15

    const int w    = threadIdx.x >> 6;                // 0..3: chunk split
    const int lane = threadIdx.x & 63;
    const int q    = lane >> 4, r = lane & 15;
    const int t    = t0 + r;                          // this lane's A row

    const float* Sb  = S    + ((size_t)b * T_ + t) * T_;
    const float* mB  = m    + (size_t)b * T_;
    const float* lB  = linv + (size_t)b * T_;
    const u16*   VtB = Vt   + (size_t)b * H_ * T_;

    floatx4 acc[8] = {};                              // 16(t) x 128(h) per wave

    for (int ci = w; ci < nchunks; ci += 4) {
        const int s0 = ci * 64;
        #pragma unroll
        for (int kk = 0; kk < 2; ++kk) {
            const int sb = s0 + kk * 32 + q * 8;
            float sv[8], mv[8], lv[8];
            *(float4*)&sv[0] = *(const float4*)&Sb[sb];
            *(float4*)&sv[4] = *(const float4*)&Sb[sb + 4];
            *(float4*)&mv[0] = *(const float4*)&mB[sb];
            *(float4*)&mv[4] = *(const float4*)&mB[sb + 4];
            *(float4*)&lv[0] = *(const float4*)&lB[sb];
            *(float4*)&lv[4] = *(const float4*)&lB[sb + 4];

            short8 af;
            #pragma unroll
            for (int j = 0; j < 8; ++j) {
                float wj = 0.f;
                if (sb + j <= t) wj = __expf(sv[j] - mv[j]) * lv[j];
                af[j] = (short)f2bf(wj);
            }
            #pragma unroll
            for (int nt = 0; nt < 8; ++nt) {
                short8 bf = *(const short8*)&VtB[(size_t)(16 * nt + r) * T_ + sb];
                acc[nt] = __builtin_amdgcn_mfma_f32_16x16x32_bf16(af, bf, acc[nt], 0, 0, 0);
            }
        }
    }

    // cross-wave reduction: red[w][tr*128 + h], tr = q*4+reg, h = 16*nt+r
    __shared__ float red[4][16 * 128];                // 32 KB
    #pragma unroll
    for (int nt = 0; nt < 8; ++nt)
        #pragma unroll
        for (int reg = 0; reg < 4; ++reg)
            red[w][(q * 4 + reg) * 128 + 16 * nt + r] = acc[nt][reg];
    __syncthreads();

    float* outB = out + ((size_t)b * T_ + t0) * H_;   // [16][128] contiguous
    for (int i = threadIdx.x; i < 16 * 128; i += 256)
        outB[i] = red[0][i] + red[1][i] + red[2][i] + red[3][i];
}

// ---------------------------------------------------------------------------
extern "C" void kernel_launch(void* const* d_in, const int* in_sizes, int n_in,
                              void* d_out, int out_size, void* d_ws, size_t ws_size,
                              hipStream_t stream) {
    const float* x  = (const float*)d_in[0];
    const float* Wq = (const float*)d_in[1];
    const float* Wk = (const float*)d_in[2];
    const float* Wv = (const float*)d_in[3];
    float* out = (float*)d_out;

    // workspace: S fp32 [B*T*T], m,linv fp32 [B*T], Qb,Kb bf16 [B*T*H], Vt bf16 [B*H*T]
    float* S  = (float*)d_ws;                          // 64 MB
    float* m  = S + (size_t)B_ * T_ * T_;
    float* l  = m + (size_t)B_ * T_;
    u16*   Qb = (u16*)(l + (size_t)B_ * T_);
    u16*   Kb = Qb + (size_t)B_ * T_ * H_;             // 2 MB each
    u16*   Vt = Kb + (size_t)B_ * T_ * H_;
    // total ~70.1 MB (round-1 layout used 80.8 MB, so ws_size suffices)

    // stats partials staged in d_out (1 MB << 4 MB), consumed before out_kernel
    float* pm = (float*)d_out;
    float* pl = pm + (size_t)B_ * NCHUNK * T_;

    qkv_kernel   <<<dim3(B_ * T_ / 8),            dim3(128), 0, stream>>>(x, Wq, Wk, Wv, Qb, Kb, Vt);
    scores_kernel<<<dim3(32, 16, B_),             dim3(256), 0, stream>>>(Qb, Kb, S);
    stats_partial_kernel<<<dim3(T_ / 256, NCHUNK, B_), dim3(256), 0, stream>>>(S, pm, pl);
    stats_reduce_kernel <<<dim3(B_ * T_ / 256),   dim3(256), 0, stream>>>(pm, pl, m, l);
    out_kernel   <<<dim3(T_ / 16, B_),            dim3(256), 0, stream>>>(S, Vt, m, l, out);
}

// Round 5
// 234.808 us; speedup vs baseline: 4.8852x; 1.2794x over previous
//
#include <hip/hip_runtime.h>
#include <math.h>

#define B_ 4
#define T_ 2048
#define C_ 1024
#define H_ 128
#define RCHUNK 128                 // rows per stats partial chunk
#define NCHUNK (T_ / RCHUNK)       // 16 chunks

typedef unsigned short u16;
typedef short short8 __attribute__((ext_vector_type(8)));   // 8 bf16 = 4 VGPRs
typedef short short4v __attribute__((ext_vector_type(4)));  // 8B
typedef float floatx4 __attribute__((ext_vector_type(4)));  // MFMA C/D

// fp32 -> bf16 round-to-nearest-even
__device__ __forceinline__ u16 f2bf(float f) {
    union { float f; unsigned int u; } v; v.f = f;
    return (u16)((v.u + 0x7fffu + ((v.u >> 16) & 1u)) >> 16);
}

// ---------------------------------------------------------------------------
// Kernel A0: x fp32 -> xb bf16 (8 elems/thread, 16B stores).
// ---------------------------------------------------------------------------
__global__ __launch_bounds__(256) void convert_x_kernel(
    const float* __restrict__ x, u16* __restrict__ xb)
{
    const size_t i = ((size_t)blockIdx.x * 256 + threadIdx.x) * 8;
    float4 a = *(const float4*)&x[i];
    float4 b = *(const float4*)&x[i + 4];
    short8 o;
    o[0]=(short)f2bf(a.x); o[1]=(short)f2bf(a.y); o[2]=(short)f2bf(a.z); o[3]=(short)f2bf(a.w);
    o[4]=(short)f2bf(b.x); o[5]=(short)f2bf(b.y); o[6]=(short)f2bf(b.z); o[7]=(short)f2bf(b.w);
    *(short8*)&xb[i] = o;
}

// ---------------------------------------------------------------------------
// Kernel A1: W [C][H] fp32 -> Wt [3][H][C] bf16 (transposed for MFMA B-frags).
// LDS-tiled 64x64 transpose. grid (C/64, H/64, 3).
// ---------------------------------------------------------------------------
__global__ __launch_bounds__(256) void convert_w_kernel(
    const float* __restrict__ Wq, const float* __restrict__ Wk,
    const float* __restrict__ Wv, u16* __restrict__ Wt)
{
    const int k0 = blockIdx.x * 64, n0 = blockIdx.y * 64, widx = blockIdx.z;
    const float* W = (widx == 0) ? Wq : (widx == 1) ? Wk : Wv;

    __shared__ float ts[64][68];                // +4 pad
    for (int i = threadIdx.x; i < 64 * 16; i += 256) {
        int r = i >> 4, c4 = i & 15;
        float4 v = *(const float4*)&W[(size_t)(k0 + r) * H_ + n0 + c4 * 4];
        ts[r][c4 * 4 + 0] = v.x; ts[r][c4 * 4 + 1] = v.y;
        ts[r][c4 * 4 + 2] = v.z; ts[r][c4 * 4 + 3] = v.w;
    }
    __syncthreads();
    for (int i = threadIdx.x; i < 64 * 16; i += 256) {
        int n = i >> 4, k4 = i & 15;
        short4v o;
        #pragma unroll
        for (int j = 0; j < 4; ++j) o[j] = (short)f2bf(ts[k4 * 4 + j][n]);
        *(short4v*)&Wt[(size_t)widx * H_ * C_ + (size_t)(n0 + n) * C_ + k0 + k4 * 4] = o;
    }
}

// ---------------------------------------------------------------------------
// Kernel A2 (MFMA): QKV projection.  out[m][n] = sum_k xb[m][k] * Wt[n][k].
// grid (M/64, 3); block 256 = 4 waves; tile 64(m) x 128(n); BK=128, 8 iters.
// Writes Q,K bf16 row-major [B*T][H]; V row-major staged in d_out.
// ---------------------------------------------------------------------------
__global__ __launch_bounds__(256) void qkv_gemm_kernel(
    const u16* __restrict__ xb, const u16* __restrict__ Wt,
    u16* __restrict__ Qb, u16* __restrict__ Kb, u16* __restrict__ Vb)
{
    const int m0   = blockIdx.x * 64;
    const int widx = blockIdx.y;
    const u16* Wg = Wt + (size_t)widx * H_ * C_;

    __shared__ u16 As[64 * 136];                // 17.4 KB
    __shared__ u16 Bs[128 * 136];               // 34.8 KB

    const int w    = threadIdx.x >> 6;          // wave -> m rows [16w,16w+16)
    const int lane = threadIdx.x & 63;
    const int q    = lane >> 4, r = lane & 15;

    floatx4 acc[8] = {};                        // 16(m) x 128(n)

    for (int k0 = 0; k0 < C_; k0 += 128) {
        for (int i = threadIdx.x; i < 64 * 16; i += 256) {
            int rr = i >> 4, c = i & 15;
            *(float4*)&As[rr * 136 + c * 8] =
                *(const float4*)&xb[(size_t)(m0 + rr) * C_ + k0 + c * 8];
        }
        for (int i = threadIdx.x; i < 128 * 16; i += 256) {
            int rr = i >> 4, c = i & 15;
            *(float4*)&Bs[rr * 136 + c * 8] =
                *(const float4*)&Wg[(size_t)rr * C_ + k0 + c * 8];
        }
        __syncthreads();

        #pragma unroll
        for (int kk = 0; kk < 4; ++kk) {
            short8 af = *(const short8*)&As[(16 * w + r) * 136 + kk * 32 + q * 8];
            #pragma unroll
            for (int nt = 0; nt < 8; ++nt) {
                short8 bf = *(const short8*)&Bs[(16 * nt + r) * 136 + kk * 32 + q * 8];
                acc[nt] = __builtin_amdgcn_mfma_f32_16x16x32_bf16(af, bf, acc[nt], 0, 0, 0);
            }
        }
        __syncthreads();
    }

    u16* dst = (widx == 0) ? Qb : (widx == 1) ? Kb : Vb;
    #pragma unroll
    for (int nt = 0; nt < 8; ++nt)
        #pragma unroll
        for (int reg = 0; reg < 4; ++reg) {
            int mm = m0 + 16 * w + q * 4 + reg;     // C/D row map
            int nn = 16 * nt + r;                   // C/D col map
            dst[(size_t)mm * H_ + nn] = f2bf(acc[nt][reg]);
        }
}

// ---------------------------------------------------------------------------
// Kernel A3: V row-major bf16 [b][t][h] -> Vt [b][h][t]. LDS 64x64 tiles.
// ---------------------------------------------------------------------------
__global__ __launch_bounds__(256) void transpose_v_kernel(
    const u16* __restrict__ Vb, u16* __restrict__ Vt)
{
    const int t0 = blockIdx.x * 64, h0 = blockIdx.y * 64, b = blockIdx.z;
    __shared__ u16 ts[64][72];                  // +8 pad

    for (int i = threadIdx.x; i < 64 * 8; i += 256) {
        int r = i >> 3, c8 = i & 7;
        *(float4*)&ts[r][c8 * 8] =
            *(const float4*)&Vb[((size_t)(b * T_ + t0 + r)) * H_ + h0 + c8 * 8];
    }
    __syncthreads();
    for (int i = threadIdx.x; i < 64 * 8; i += 256) {
        int h = i >> 3, t8 = i & 7;
        short8 o;
        #pragma unroll
        for (int j = 0; j < 8; ++j) o[j] = (short)ts[t8 * 8 + j][h];
        *(short8*)&Vt[((size_t)b * H_ + h0 + h) * T_ + t0 + t8 * 8] = o;
    }
}

// ---------------------------------------------------------------------------
// Kernel B1 (MFMA): S[b,t,s] = scale * Q·K^T, lower-triangle tiles only.
// ---------------------------------------------------------------------------
__global__ __launch_bounds__(256) void scores_kernel(
    const u16* __restrict__ Qb, const u16* __restrict__ Kb,
    float* __restrict__ S)
{
    const int si = blockIdx.x;                  // 0..31 (s tile, 64 wide)
    const int ti = blockIdx.y;                  // 0..15 (t tile, 128 tall)
    const int b  = blockIdx.z;
    if (si > 2 * ti + 1) return;                // strictly-upper tiles unused
    const int t0 = ti * 128, s0 = si * 64;

    __shared__ u16 Qs[128 * 136];               // 34.8 KB
    __shared__ u16 Ks[64 * 136];                // 17.4 KB

    const u16* Qg = Qb + ((size_t)b * T_ + t0) * H_;
    const u16* Kg = Kb + ((size_t)b * T_ + s0) * H_;

    for (int i = threadIdx.x; i < 128 * 16; i += 256) {
        int r = i >> 4, c = i & 15;
        *(float4*)&Qs[r * 136 + c * 8] = *(const float4*)&Qg[(size_t)r * H_ + c * 8];
    }
    for (int i = threadIdx.x; i < 64 * 16; i += 256) {
        int r = i >> 4, c = i & 15;
        *(float4*)&Ks[r * 136 + c * 8] = *(const float4*)&Kg[(size_t)r * H_ + c * 8];
    }
    __syncthreads();

    const int w    = threadIdx.x >> 6;          // wave -> t rows [32w,32w+32)
    const int lane = threadIdx.x & 63;
    const int q    = lane >> 4, r = lane & 15;

    floatx4 acc[2][4] = {};
    #pragma unroll
    for (int kk = 0; kk < 4; ++kk) {
        short8 a0 = *(const short8*)&Qs[(32 * w +      r) * 136 + kk * 32 + q * 8];
        short8 a1 = *(const short8*)&Qs[(32 * w + 16 + r) * 136 + kk * 32 + q * 8];
        #pragma unroll
        for (int nt = 0; nt < 4; ++nt) {
            short8 bf = *(const short8*)&Ks[(16 * nt + r) * 136 + kk * 32 + q * 8];
            acc[0][nt] = __builtin_amdgcn_mfma_f32_16x16x32_bf16(a0, bf, acc[0][nt], 0, 0, 0);
            acc[1][nt] = __builtin_amdgcn_mfma_f32_16x16x32_bf16(a1, bf, acc[1][nt], 0, 0, 0);
        }
    }

    const float scale = 0.08838834764831845f;   // 1/sqrt(128)
    #pragma unroll
    for (int mt = 0; mt < 2; ++mt)
        #pragma unroll
        for (int nt = 0; nt < 4; ++nt)
            #pragma unroll
            for (int reg = 0; reg < 4; ++reg) {
                int t = t0 + 32 * w + 16 * mt + q * 4 + reg;
                int s = s0 + 16 * nt + r;
                S[((size_t)b * T_ + t) * T_ + s] = acc[mt][nt][reg] * scale;
            }
}

// ---------------------------------------------------------------------------
// Kernel B2a: PARTIAL per-key-column stats over a 128-row chunk.
// ---------------------------------------------------------------------------
__global__ __launch_bounds__(256) void stats_partial_kernel(
    const float* __restrict__ S, float* __restrict__ pm, float* __restrict__ pl)
{
    const int b  = blockIdx.z;
    const int r0 = blockIdx.y * RCHUNK;
    const int s0 = blockIdx.x * 256;
    const int s  = s0 + threadIdx.x;
    const size_t oidx = ((size_t)b * NCHUNK + blockIdx.y) * T_ + s;

    float mx = -INFINITY, sum = 0.f;
    if (r0 + RCHUNK > s0) {
        const float* Sb = S + (size_t)b * T_ * T_;
        for (int t = r0; t < r0 + RCHUNK; ++t) {
            if (t >= s) {
                float v  = Sb[(size_t)t * T_ + s];
                float mn = fmaxf(mx, v);
                sum = sum * __expf(mx - mn) + __expf(v - mn);
                mx  = mn;
            }
        }
    }
    pm[oidx] = mx;
    pl[oidx] = sum;
}

// ---------------------------------------------------------------------------
// Kernel B2b: combine partials; stores 1/L.
// ---------------------------------------------------------------------------
__global__ __launch_bounds__(256) void stats_reduce_kernel(
    const float* __restrict__ pm, const float* __restrict__ pl,
    float* __restrict__ m, float* __restrict__ linv)
{
    const int idx = blockIdx.x * 256 + threadIdx.x;   // b*T + s
    const int b = idx / T_, s = idx - b * T_;

    float M = -INFINITY;
    #pragma unroll
    for (int c = 0; c < NCHUNK; ++c)
        M = fmaxf(M, pm[((size_t)b * NCHUNK + c) * T_ + s]);

    float L = 0.f;
    #pragma unroll
    for (int c = 0; c < NCHUNK; ++c) {
        float mc = pm[((size_t)b * NCHUNK + c) * T_ + s];
        float lc = pl[((size_t)b * NCHUNK + c) * T_ + s];
        if (lc > 0.f) L += lc * __expf(mc - M);
    }
    m[idx]    = M;
    linv[idx] = 1.0f / L;
}

// ---------------------------------------------------------------------------
// Kernel B3 (MFMA, register-resident): out = P @ V, 4-way split-s per block.
// ---------------------------------------------------------------------------
__global__ __launch_bounds__(256) void out_kernel(
    const float* __restrict__ S, const u16* __restrict__ Vt,
    const float* __restrict__ m, const float* __restrict__ linv,
    float* __restrict__ out)
{
    const int b  = blockIdx.y;
    const int tb = (int)(gridDim.x - 1 - blockIdx.x); // heavy tiles first
    const int t0 = tb * 16;
    const int nchunks = (t0 + 79) >> 6;               // s0 <= t0+15

    const int w    = threadIdx.x >> 6;                // 0..3: chunk split
    const int lane = threadIdx.x & 63;
    const int q    = lane >> 4, r = lane & 15;
    const int t    = t0 + r;                          // this lane's A row

    const float* Sb  = S    + ((size_t)b * T_ + t) * T_;
    const float* mB  = m    + (size_t)b * T_;
    const float* lB  = linv + (size_t)b * T_;
    const u16*   VtB = Vt   + (size_t)b * H_ * T_;

    floatx4 acc[8] = {};

    for (int ci = w; ci < nchunks; ci += 4) {
        const int s0 = ci * 64;
        #pragma unroll
        for (int kk = 0; kk < 2; ++kk) {
            const int sb = s0 + kk * 32 + q * 8;
            float sv[8], mv[8], lv[8];
            *(float4*)&sv[0] = *(const float4*)&Sb[sb];
            *(float4*)&sv[4] = *(const float4*)&Sb[sb + 4];
            *(float4*)&mv[0] = *(const float4*)&mB[sb];
            *(float4*)&mv[4] = *(const float4*)&mB[sb + 4];
            *(float4*)&lv[0] = *(const float4*)&lB[sb];
            *(float4*)&lv[4] = *(const float4*)&lB[sb + 4];

            short8 af;
            #pragma unroll
            for (int j = 0; j < 8; ++j) {
                float wj = 0.f;
                if (sb + j <= t) wj = __expf(sv[j] - mv[j]) * lv[j];
                af[j] = (short)f2bf(wj);
            }
            #pragma unroll
            for (int nt = 0; nt < 8; ++nt) {
                short8 bf = *(const short8*)&VtB[(size_t)(16 * nt + r) * T_ + sb];
                acc[nt] = __builtin_amdgcn_mfma_f32_16x16x32_bf16(af, bf, acc[nt], 0, 0, 0);
            }
        }
    }

    __shared__ float red[4][16 * 128];                // 32 KB
    #pragma unroll
    for (int nt = 0; nt < 8; ++nt)
        #pragma unroll
        for (int reg = 0; reg < 4; ++reg)
            red[w][(q * 4 + reg) * 128 + 16 * nt + r] = acc[nt][reg];
    __syncthreads();

    float* outB = out + ((size_t)b * T_ + t0) * H_;
    for (int i = threadIdx.x; i < 16 * 128; i += 256)
        outB[i] = red[0][i] + red[1][i] + red[2][i] + red[3][i];
}

// ---------------------------------------------------------------------------
extern "C" void kernel_launch(void* const* d_in, const int* in_sizes, int n_in,
                              void* d_out, int out_size, void* d_ws, size_t ws_size,
                              hipStream_t stream) {
    const float* x  = (const float*)d_in[0];
    const float* Wq = (const float*)d_in[1];
    const float* Wk = (const float*)d_in[2];
    const float* Wv = (const float*)d_in[3];
    float* out = (float*)d_out;

    // workspace: S fp32 [B*T*T] (first 16 MB aliased as xb bf16 — consumed by
    // qkv_gemm before scores writes S), m, linv, Wt, Qb, Kb, Vt.
    float* S    = (float*)d_ws;                        // 64 MB
    float* m    = S + (size_t)B_ * T_ * T_;
    float* linv = m + (size_t)B_ * T_;
    u16*   Wt   = (u16*)(linv + (size_t)B_ * T_);      // 0.75 MB
    u16*   Qb   = Wt + (size_t)3 * H_ * C_;            // 2 MB
    u16*   Kb   = Qb + (size_t)B_ * T_ * H_;           // 2 MB
    u16*   Vt   = Kb + (size_t)B_ * T_ * H_;           // 2 MB
    u16*   xb   = (u16*)S;                             // 16 MB alias
    // total ~70.8 MB (round-1 layout used 80.8 MB, so ws_size suffices)

    // d_out staging: Vb (2 MB) consumed by transpose_v; then pm/pl (1 MB)
    // consumed by stats_reduce; then final out (4 MB) overwrites.
    u16*   Vb = (u16*)d_out;
    float* pm = (float*)d_out;
    float* pl = pm + (size_t)B_ * NCHUNK * T_;

    convert_x_kernel  <<<dim3(B_ * T_ * C_ / (256 * 8)), dim3(256), 0, stream>>>(x, xb);
    convert_w_kernel  <<<dim3(C_ / 64, H_ / 64, 3),      dim3(256), 0, stream>>>(Wq, Wk, Wv, Wt);
    qkv_gemm_kernel   <<<dim3(B_ * T_ / 64, 3),          dim3(256), 0, stream>>>(xb, Wt, Qb, Kb, Vb);
    transpose_v_kernel<<<dim3(T_ / 64, H_ / 64, B_),     dim3(256), 0, stream>>>(Vb, Vt);
    scores_kernel     <<<dim3(32, 16, B_),               dim3(256), 0, stream>>>(Qb, Kb, S);
    stats_partial_kernel<<<dim3(T_ / 256, NCHUNK, B_),   dim3(256), 0, stream>>>(S, pm, pl);
    stats_reduce_kernel <<<dim3(B_ * T_ / 256),          dim3(256), 0, stream>>>(pm, pl, m, linv);
    out_kernel        <<<dim3(T_ / 16, B_),              dim3(256), 0, stream>>>(S, Vt, m, linv, out);
}

// Round 6
// 183.874 us; speedup vs baseline: 6.2385x; 1.2770x over previous
//
#include <hip/hip_runtime.h>
#include <math.h>

#define B_ 4
#define T_ 2048
#define C_ 1024
#define H_ 128
#define RCHUNK 128                 // rows per stats chunk == scores t-tile
#define NCHUNK (T_ / RCHUNK)       // 16 chunks

typedef unsigned short u16;
typedef unsigned int   u32;
typedef short short8  __attribute__((ext_vector_type(8)));  // 8 bf16 = 4 VGPRs
typedef short short4v __attribute__((ext_vector_type(4)));  // 8B
typedef float floatx4 __attribute__((ext_vector_type(4)));  // MFMA C/D

// fp32 -> bf16 round-to-nearest-even
__device__ __forceinline__ u16 f2bf(float f) {
    union { float f; u32 u; } v; v.f = f;
    return (u16)((v.u + 0x7fffu + ((v.u >> 16) & 1u)) >> 16);
}
// bf16 -> fp32
__device__ __forceinline__ float bf2f(u16 h) {
    union { u32 u; float f; } v; v.u = ((u32)h) << 16;
    return v.f;
}

// ---------------------------------------------------------------------------
// Kernel A0: x fp32 -> xb bf16 (8 elems/thread, 16B stores).
// ---------------------------------------------------------------------------
__global__ __launch_bounds__(256) void convert_x_kernel(
    const float* __restrict__ x, u16* __restrict__ xb)
{
    const size_t i = ((size_t)blockIdx.x * 256 + threadIdx.x) * 8;
    float4 a = *(const float4*)&x[i];
    float4 b = *(const float4*)&x[i + 4];
    short8 o;
    o[0]=(short)f2bf(a.x); o[1]=(short)f2bf(a.y); o[2]=(short)f2bf(a.z); o[3]=(short)f2bf(a.w);
    o[4]=(short)f2bf(b.x); o[5]=(short)f2bf(b.y); o[6]=(short)f2bf(b.z); o[7]=(short)f2bf(b.w);
    *(short8*)&xb[i] = o;
}

// ---------------------------------------------------------------------------
// Kernel A1: W [C][H] fp32 -> Wt [3][H][C] bf16 (transposed for MFMA B-frags).
// ---------------------------------------------------------------------------
__global__ __launch_bounds__(256) void convert_w_kernel(
    const float* __restrict__ Wq, const float* __restrict__ Wk,
    const float* __restrict__ Wv, u16* __restrict__ Wt)
{
    const int k0 = blockIdx.x * 64, n0 = blockIdx.y * 64, widx = blockIdx.z;
    const float* W = (widx == 0) ? Wq : (widx == 1) ? Wk : Wv;

    __shared__ float ts[64][68];                // +4 pad
    for (int i = threadIdx.x; i < 64 * 16; i += 256) {
        int r = i >> 4, c4 = i & 15;
        float4 v = *(const float4*)&W[(size_t)(k0 + r) * H_ + n0 + c4 * 4];
        ts[r][c4 * 4 + 0] = v.x; ts[r][c4 * 4 + 1] = v.y;
        ts[r][c4 * 4 + 2] = v.z; ts[r][c4 * 4 + 3] = v.w;
    }
    __syncthreads();
    for (int i = threadIdx.x; i < 64 * 16; i += 256) {
        int n = i >> 4, k4 = i & 15;
        short4v o;
        #pragma unroll
        for (int j = 0; j < 4; ++j) o[j] = (short)f2bf(ts[k4 * 4 + j][n]);
        *(short4v*)&Wt[(size_t)widx * H_ * C_ + (size_t)(n0 + n) * C_ + k0 + k4 * 4] = o;
    }
}

// ---------------------------------------------------------------------------
// Kernel A2 (MFMA): QKV projection.  out[m][n] = sum_k xb[m][k] * Wt[n][k].
// grid (M/64, 3); block 256 = 4 waves; tile 64(m) x 128(n); BK=128.
// widx 0/1 -> Q,K bf16 row-major.  widx 2 -> V stored TRANSPOSED directly
// (C/D layout gives 4 consecutive t per lane -> 8B stores into Vt[b][h][t]).
// ---------------------------------------------------------------------------
__global__ __launch_bounds__(256) void qkv_gemm_kernel(
    const u16* __restrict__ xb, const u16* __restrict__ Wt,
    u16* __restrict__ Qb, u16* __restrict__ Kb, u16* __restrict__ Vt)
{
    const int m0   = blockIdx.x * 64;
    const int widx = blockIdx.y;
    const u16* Wg = Wt + (size_t)widx * H_ * C_;

    __shared__ u16 As[64 * 136];                // 17.4 KB
    __shared__ u16 Bs[128 * 136];               // 34.8 KB

    const int w    = threadIdx.x >> 6;          // wave -> m rows [16w,16w+16)
    const int lane = threadIdx.x & 63;
    const int q    = lane >> 4, r = lane & 15;

    floatx4 acc[8] = {};                        // 16(m) x 128(n)

    for (int k0 = 0; k0 < C_; k0 += 128) {
        for (int i = threadIdx.x; i < 64 * 16; i += 256) {
            int rr = i >> 4, c = i & 15;
            *(float4*)&As[rr * 136 + c * 8] =
                *(const float4*)&xb[(size_t)(m0 + rr) * C_ + k0 + c * 8];
        }
        for (int i = threadIdx.x; i < 128 * 16; i += 256) {
            int rr = i >> 4, c = i & 15;
            *(float4*)&Bs[rr * 136 + c * 8] =
                *(const float4*)&Wg[(size_t)rr * C_ + k0 + c * 8];
        }
        __syncthreads();

        #pragma unroll
        for (int kk = 0; kk < 4; ++kk) {
            short8 af = *(const short8*)&As[(16 * w + r) * 136 + kk * 32 + q * 8];
            #pragma unroll
            for (int nt = 0; nt < 8; ++nt) {
                short8 bf = *(const short8*)&Bs[(16 * nt + r) * 136 + kk * 32 + q * 8];
                acc[nt] = __builtin_amdgcn_mfma_f32_16x16x32_bf16(af, bf, acc[nt], 0, 0, 0);
            }
        }
        __syncthreads();
    }

    if (widx == 2) {
        const int bb  = m0 / T_;                // 64-row tile never spans b
        const int tt0 = (m0 - bb * T_) + 16 * w + q * 4;
        #pragma unroll
        for (int nt = 0; nt < 8; ++nt) {
            short4v o;
            #pragma unroll
            for (int reg = 0; reg < 4; ++reg) o[reg] = (short)f2bf(acc[nt][reg]);
            *(short4v*)&Vt[((size_t)bb * H_ + 16 * nt + r) * T_ + tt0] = o;
        }
    } else {
        u16* dst = (widx == 0) ? Qb : Kb;
        #pragma unroll
        for (int nt = 0; nt < 8; ++nt)
            #pragma unroll
            for (int reg = 0; reg < 4; ++reg) {
                int mm = m0 + 16 * w + q * 4 + reg;     // C/D row map
                int nn = 16 * nt + r;                   // C/D col map
                dst[(size_t)mm * H_ + nn] = f2bf(acc[nt][reg]);
            }
    }
}

// ---------------------------------------------------------------------------
// Kernel B1 (MFMA, fused stats): S tile = scale * Q·K^T (lower triangle),
// written as BF16 via LDS transpose (coalesced 16B row stores), PLUS
// per-128-row-chunk column stats (pm,pl) computed straight from the
// accumulators: lane-local masked max/sumexp over its 8 rows per column ->
// LDS [16 groups][64 cols] -> 64-thread combine.  t-tile == RCHUNK, so
// chunk index == ti.  Eliminates the stats_partial S re-read entirely.
// ---------------------------------------------------------------------------
__global__ __launch_bounds__(256) void scores_kernel(
    const u16* __restrict__ Qb, const u16* __restrict__ Kb,
    u16* __restrict__ S, float* __restrict__ pm, float* __restrict__ pl)
{
    const int si = blockIdx.x;                  // 0..31 (s tile, 64 wide)
    const int ti = blockIdx.y;                  // 0..15 (t tile, 128 tall)
    const int b  = blockIdx.z;
    if (si > 2 * ti + 1) return;                // strictly-upper tiles unused
    const int t0 = ti * 128, s0 = si * 64;
    const bool diag = (si >= 2 * ti);           // tile touches the diagonal

    __shared__ u16 smem[128 * 136 + 64 * 136];  // 52.2 KB: Qs | Ks, then reused
    u16* Qs = smem;
    u16* Ks = smem + 128 * 136;

    const u16* Qg = Qb + ((size_t)b * T_ + t0) * H_;
    const u16* Kg = Kb + ((size_t)b * T_ + s0) * H_;

    for (int i = threadIdx.x; i < 128 * 16; i += 256) {
        int rr = i >> 4, c = i & 15;
        *(float4*)&Qs[rr * 136 + c * 8] = *(const float4*)&Qg[(size_t)rr * H_ + c * 8];
    }
    for (int i = threadIdx.x; i < 64 * 16; i += 256) {
        int rr = i >> 4, c = i & 15;
        *(float4*)&Ks[rr * 136 + c * 8] = *(const float4*)&Kg[(size_t)rr * H_ + c * 8];
    }
    __syncthreads();

    const int w    = threadIdx.x >> 6;          // wave -> t rows [32w,32w+32)
    const int lane = threadIdx.x & 63;
    const int q    = lane >> 4, r = lane & 15;

    floatx4 acc[2][4] = {};
    #pragma unroll
    for (int kk = 0; kk < 4; ++kk) {
        short8 a0 = *(const short8*)&Qs[(32 * w +      r) * 136 + kk * 32 + q * 8];
        short8 a1 = *(const short8*)&Qs[(32 * w + 16 + r) * 136 + kk * 32 + q * 8];
        #pragma unroll
        for (int nt = 0; nt < 4; ++nt) {
            short8 bf = *(const short8*)&Ks[(16 * nt + r) * 136 + kk * 32 + q * 8];
            acc[0][nt] = __builtin_amdgcn_mfma_f32_16x16x32_bf16(a0, bf, acc[0][nt], 0, 0, 0);
            acc[1][nt] = __builtin_amdgcn_mfma_f32_16x16x32_bf16(a1, bf, acc[1][nt], 0, 0, 0);
        }
    }
    __syncthreads();                            // everyone done with Qs/Ks

    // ---- reuse smem: bf16 tile [128][72] + stats red arrays -------------
    u16*   tile = smem;                         // 18.4 KB
    float* redm = (float*)(smem + 128 * 72);    // [16][64]
    float* redl = redm + 16 * 64;               // [16][64]

    const float scale = 0.08838834764831845f;   // 1/sqrt(128)
    #pragma unroll
    for (int nt = 0; nt < 4; ++nt) {
        const int s = s0 + 16 * nt + r;
        float mx = -INFINITY, sm = 0.f;
        #pragma unroll
        for (int mt = 0; mt < 2; ++mt)
            #pragma unroll
            for (int reg = 0; reg < 4; ++reg) {
                const int tl = 32 * w + 16 * mt + q * 4 + reg;
                const float v = acc[mt][nt][reg] * scale;
                tile[tl * 72 + 16 * nt + r] = f2bf(v);
                if (!diag || (t0 + tl) >= s) {          // mask upper triangle
                    float mn = fmaxf(mx, v);
                    sm = sm * __expf(mx - mn) + __expf(v - mn);
                    mx = mn;
                }
            }
        redm[(4 * w + q) * 64 + 16 * nt + r] = mx;
        redl[(4 * w + q) * 64 + 16 * nt + r] = sm;
    }
    __syncthreads();

    if (threadIdx.x < 64) {                     // combine 16 row-groups/col
        const int c = threadIdx.x;
        float M = -INFINITY;
        #pragma unroll
        for (int g = 0; g < 16; ++g) M = fmaxf(M, redm[g * 64 + c]);
        float L = 0.f;
        #pragma unroll
        for (int g = 0; g < 16; ++g) {
            float lg = redl[g * 64 + c];
            if (lg > 0.f) L += lg * __expf(redm[g * 64 + c] - M);
        }
        const size_t o = ((size_t)b * NCHUNK + ti) * T_ + s0 + c;
        pm[o] = M;
        pl[o] = L;
    }

    // coalesced bf16 tile store: 128 rows x 128B
    u16* Sg = S + ((size_t)b * T_ + t0) * T_ + s0;
    for (int i = threadIdx.x; i < 128 * 8; i += 256) {
        int tl = i >> 3, c8 = i & 7;
        *(float4*)&Sg[(size_t)tl * T_ + c8 * 8] = *(float4*)&tile[tl * 72 + c8 * 8];
    }
}

// ---------------------------------------------------------------------------
// Kernel B2: combine chunk partials (chunks c >= s>>7 exist); stores 1/L.
// ---------------------------------------------------------------------------
__global__ __launch_bounds__(256) void stats_reduce_kernel(
    const float* __restrict__ pm, const float* __restrict__ pl,
    float* __restrict__ m, float* __restrict__ linv)
{
    const int idx = blockIdx.x * 256 + threadIdx.x;   // b*T + s
    const int b = idx >> 11, s = idx & (T_ - 1);
    const int c0 = s >> 7;                            // first chunk with t>=s

    float M = -INFINITY;
    for (int c = c0; c < NCHUNK; ++c)
        M = fmaxf(M, pm[((size_t)b * NCHUNK + c) * T_ + s]);

    float L = 0.f;
    for (int c = c0; c < NCHUNK; ++c) {
        float mc = pm[((size_t)b * NCHUNK + c) * T_ + s];
        float lc = pl[((size_t)b * NCHUNK + c) * T_ + s];
        if (lc > 0.f) L += lc * __expf(mc - M);
    }
    m[idx]    = M;
    linv[idx] = 1.0f / L;
}

// ---------------------------------------------------------------------------
// Kernel B3 (MFMA, register-resident): out = P @ V, P = exp(S-m[s])*linv[s],
// masked s <= t.  S now BF16 (half the read traffic).  4-way split-s.
// ---------------------------------------------------------------------------
__global__ __launch_bounds__(256) void out_kernel(
    const u16* __restrict__ S, const u16* __restrict__ Vt,
    const float* __restrict__ m, const float* __restrict__ linv,
    float* __restrict__ out)
{
    const int b  = blockIdx.y;
    const int tb = (int)(gridDim.x - 1 - blockIdx.x); // heavy tiles first
    const int t0 = tb * 16;
    const int nchunks = (t0 + 79) >> 6;               // s0 <= t0+15

    const int w    = threadIdx.x >> 6;                // 0..3: chunk split
    const int lane = threadIdx.x & 63;
    const int q    = lane >> 4, r = lane & 15;
    const int t    = t0 + r;                          // this lane's A row

    const u16*   Sb  = S    + ((size_t)b * T_ + t) * T_;
    const float* mB  = m    + (size_t)b * T_;
    const float* lB  = linv + (size_t)b * T_;
    const u16*   VtB = Vt   + (size_t)b * H_ * T_;

    floatx4 acc[8] = {};

    for (int ci = w; ci < nchunks; ci += 4) {
        const int s0 = ci * 64;
        #pragma unroll
        for (int kk = 0; kk < 2; ++kk) {
            const int sb = s0 + kk * 32 + q * 8;
            short8 sraw = *(const short8*)&Sb[sb];    // 8 bf16 = 16B
            float mv[8], lv[8];
            *(float4*)&mv[0] = *(const float4*)&mB[sb];
            *(float4*)&mv[4] = *(const float4*)&mB[sb + 4];
            *(float4*)&lv[0] = *(const float4*)&lB[sb];
            *(float4*)&lv[4] = *(const float4*)&lB[sb + 4];

            short8 af;
            #pragma unroll
            for (int j = 0; j < 8; ++j) {
                float wj = 0.f;
                if (sb + j <= t)
                    wj = __expf(bf2f((u16)sraw[j]) - mv[j]) * lv[j];
                af[j] = (short)f2bf(wj);
            }
            #pragma unroll
            for (int nt = 0; nt < 8; ++nt) {
                short8 bf = *(const short8*)&VtB[(size_t)(16 * nt + r) * T_ + sb];
                acc[nt] = __builtin_amdgcn_mfma_f32_16x16x32_bf16(af, bf, acc[nt], 0, 0, 0);
            }
        }
    }

    __shared__ float red[4][16 * 128];                // 32 KB
    #pragma unroll
    for (int nt = 0; nt < 8; ++nt)
        #pragma unroll
        for (int reg = 0; reg < 4; ++reg)
            red[w][(q * 4 + reg) * 128 + 16 * nt + r] = acc[nt][reg];
    __syncthreads();

    float* outB = out + ((size_t)b * T_ + t0) * H_;
    for (int i = threadIdx.x; i < 16 * 128; i += 256)
        outB[i] = red[0][i] + red[1][i] + red[2][i] + red[3][i];
}

// ---------------------------------------------------------------------------
extern "C" void kernel_launch(void* const* d_in, const int* in_sizes, int n_in,
                              void* d_out, int out_size, void* d_ws, size_t ws_size,
                              hipStream_t stream) {
    const float* x  = (const float*)d_in[0];
    const float* Wq = (const float*)d_in[1];
    const float* Wk = (const float*)d_in[2];
    const float* Wv = (const float*)d_in[3];
    float* out = (float*)d_out;

    // workspace: S bf16 [B*T*T] (32 MB; first 16 MB aliased as xb, consumed
    // by qkv_gemm before scores writes S), m, linv, Wt, Qb, Kb, Vt.
    u16*   S    = (u16*)d_ws;                          // 32 MB
    float* m    = (float*)(S + (size_t)B_ * T_ * T_);
    float* linv = m + (size_t)B_ * T_;
    u16*   Wt   = (u16*)(linv + (size_t)B_ * T_);      // 0.75 MB
    u16*   Qb   = Wt + (size_t)3 * H_ * C_;            // 2 MB
    u16*   Kb   = Qb + (size_t)B_ * T_ * H_;           // 2 MB
    u16*   Vt   = Kb + (size_t)B_ * T_ * H_;           // 2 MB
    u16*   xb   = S;                                   // 16 MB alias
    // total ~39 MB (well under proven ws_size)

    // d_out staging: pm/pl (1 MB) written by scores, read by stats_reduce,
    // then out_kernel overwrites all 4 MB.
    float* pm = (float*)d_out;
    float* pl = pm + (size_t)B_ * NCHUNK * T_;

    convert_x_kernel  <<<dim3(B_ * T_ * C_ / (256 * 8)), dim3(256), 0, stream>>>(x, xb);
    convert_w_kernel  <<<dim3(C_ / 64, H_ / 64, 3),      dim3(256), 0, stream>>>(Wq, Wk, Wv, Wt);
    qkv_gemm_kernel   <<<dim3(B_ * T_ / 64, 3),          dim3(256), 0, stream>>>(xb, Wt, Qb, Kb, Vt);
    scores_kernel     <<<dim3(32, 16, B_),               dim3(256), 0, stream>>>(Qb, Kb, S, pm, pl);
    stats_reduce_kernel<<<dim3(B_ * T_ / 256),           dim3(256), 0, stream>>>(pm, pl, m, linv);
    out_kernel        <<<dim3(T_ / 16, B_),              dim3(256), 0, stream>>>(S, Vt, m, linv, out);
}